// Round 8
// baseline (672.555 us; speedup 1.0000x reference)
//
#include <hip/hip_runtime.h>
#include <math.h>

// ---------------------------------------------------------------------------
// TransformerBlockQuantum — round 8
//  attn v4: 48 KB LDS (3 blocks/CU), reg-staged K/V prefetch, halved P buffer,
//           coalesced epilogue. GEMMs: dbuf global_load_lds, 1 barrier/K-step.
// ---------------------------------------------------------------------------

#define B_    4
#define S_    2048
#define D_    768
#define H_    12
#define DK_   64
#define FFN_  3072
#define NQ_   8
#define M_    (B_ * S_)          // 8192 rows

#define AS1 __attribute__((address_space(1)))
#define AS3 __attribute__((address_space(3)))

typedef __attribute__((ext_vector_type(8))) short bf16x8;   // 8 bf16 = 4 VGPR
typedef __attribute__((ext_vector_type(4))) float f32x4;

static __device__ __forceinline__ unsigned short f2bf(float f) {
    unsigned u = __float_as_uint(f);
    unsigned r = (u + 0x7FFFu + ((u >> 16) & 1u)) >> 16;   // RNE
    return (unsigned short)r;
}
static __device__ __forceinline__ float bf2f(unsigned short h) {
    return __uint_as_float((unsigned)h << 16);
}
static __device__ __forceinline__ bf16x8 pack8(float4 a, float4 b) {
    bf16x8 r;
    r[0] = (short)f2bf(a.x); r[1] = (short)f2bf(a.y);
    r[2] = (short)f2bf(a.z); r[3] = (short)f2bf(a.w);
    r[4] = (short)f2bf(b.x); r[5] = (short)f2bf(b.y);
    r[6] = (short)f2bf(b.z); r[7] = (short)f2bf(b.w);
    return r;
}

// ---------------------------------------------------------------------------
// Conversion: x (6291456), cw (589824), w2 (2359296) f32 -> bf16.
// ---------------------------------------------------------------------------
#define XCH  786432   // 6291456/8
#define CWCH 73728    // 589824/8
#define W2CH 294912   // 2359296/8
__global__ void convert_all(const float* __restrict__ x, const float* __restrict__ cw,
                            const float* __restrict__ w2,
                            unsigned short* __restrict__ xb, unsigned short* __restrict__ cwb,
                            unsigned short* __restrict__ w2b)
{
    int idx = blockIdx.x * 256 + threadIdx.x;     // chunk of 8 floats
    const float* src; unsigned short* dst; int c;
    if (idx < XCH)              { src = x;  dst = xb;  c = idx; }
    else if (idx < XCH + CWCH)  { src = cw; dst = cwb; c = idx - XCH; }
    else { c = idx - XCH - CWCH; if (c >= W2CH) return; src = w2; dst = w2b; }
    float4 f0 = *reinterpret_cast<const float4*>(src + (size_t)c * 8);
    float4 f1 = *reinterpret_cast<const float4*>(src + (size_t)c * 8 + 4);
    *reinterpret_cast<bf16x8*>(dst + (size_t)c * 8) = pack8(f0, f1);
}

// ---------------------------------------------------------------------------
// Flash attention v4. grid 768 (XCD-swizzled), block 256 (4 waves), 48 KB LDS
// -> 3 blocks/CU (single round). K/V reg-staged prefetch; P in two 64-col
// halves; no-max softmax; coalesced bf16x8 epilogue through P-LDS.
// ---------------------------------------------------------------------------
__global__ __launch_bounds__(256, 3)
void attn_mfma(const unsigned short* __restrict__ xb, unsigned short* __restrict__ attnb)
{
    __shared__ __align__(16) short    Ks[128 * 64];     // 16 KB
    __shared__ __align__(16) unsigned Vt32[64 * 64];    // 16 KB
    __shared__ __align__(16) short    Ps[4][32 * 64];   // 16 KB (per-wave 4 KB)

    const int tid = threadIdx.x;
    const int w   = tid >> 6;
    const int l   = tid & 63;
    const int g   = l >> 4;
    const int l15 = l & 15;

    // XCD-aware decode (proven in r7): blocks sharing (b,h) share flat%8.
    const int flat = blockIdx.x;
    const int rx = flat & 7;
    const int t  = flat >> 3;              // 0..95
    const int gq = t & 15;                 // q-tile
    const int G  = (t >> 4) * 8 + rx;      // 0..47 group (b*12+h)
    const int hh = G % 12, bb = G / 12;
    const int q0 = gq * 128;

    const unsigned short* xh = xb + ((size_t)bb * S_) * D_ + hh * DK_;

    // ---- hoist Q fragments ----
    bf16x8 qf[2][2];
    {
        const unsigned short* xq = xh + (size_t)(q0 + w * 32) * D_;
        #pragma unroll
        for (int qt = 0; qt < 2; ++qt)
            #pragma unroll
            for (int ks = 0; ks < 2; ++ks)
                qf[qt][ks] = *reinterpret_cast<const bf16x8*>(
                    xq + (size_t)(qt * 16 + l15) * D_ + ks * 32 + g * 8);
    }

    f32x4 oacc[2][4];
    float lsum[2][4];
    #pragma unroll
    for (int qt = 0; qt < 2; ++qt)
        #pragma unroll
        for (int i = 0; i < 4; ++i) {
            oacc[qt][i] = (f32x4){0.f, 0.f, 0.f, 0.f};
            lsum[qt][i] = 0.f;
        }

    short* Pw = Ps[w];
    bf16x8 kreg0, kreg1, kreg2, kreg3;     // K stage (16 VGPR)
    bf16x8 vreg0, vreg1, vreg2, vreg3;     // V stage (16 VGPR)

    auto loadK = [&](int kt) {
        const unsigned short* xk = xh + (size_t)(kt * 128) * D_;
        int c0 = tid, c1 = tid + 256, c2 = tid + 512, c3 = tid + 768;
        kreg0 = *reinterpret_cast<const bf16x8*>(xk + (size_t)(c0 >> 3) * D_ + (c0 & 7) * 8);
        kreg1 = *reinterpret_cast<const bf16x8*>(xk + (size_t)(c1 >> 3) * D_ + (c1 & 7) * 8);
        kreg2 = *reinterpret_cast<const bf16x8*>(xk + (size_t)(c2 >> 3) * D_ + (c2 & 7) * 8);
        kreg3 = *reinterpret_cast<const bf16x8*>(xk + (size_t)(c3 >> 3) * D_ + (c3 & 7) * 8);
    };
    auto writeK = [&]() {
        int c0 = tid, c1 = tid + 256, c2 = tid + 512, c3 = tid + 768;
        #define WRK(cc, rg) { int r = (cc) >> 3, b2 = (cc) & 7; \
            *reinterpret_cast<bf16x8*>(&Ks[r * 64 + ((b2 ^ (r & 7)) << 3)]) = rg; }
        WRK(c0, kreg0) WRK(c1, kreg1) WRK(c2, kreg2) WRK(c3, kreg3)
        #undef WRK
    };
    auto loadV = [&](int kt) {
        const unsigned short* ra = xh + (size_t)(kt * 128 + 2 * l) * D_ + w * 16;
        vreg0 = *reinterpret_cast<const bf16x8*>(ra);
        vreg1 = *reinterpret_cast<const bf16x8*>(ra + 8);
        vreg2 = *reinterpret_cast<const bf16x8*>(ra + D_);
        vreg3 = *reinterpret_cast<const bf16x8*>(ra + D_ + 8);
    };
    auto writeV = [&]() {
        #pragma unroll
        for (int j = 0; j < 8; ++j) {
            int d0 = w * 16 + j;
            Vt32[d0 * 64 + (l ^ ((d0 & 7) << 2))] =
                (unsigned)(unsigned short)vreg0[j] | ((unsigned)(unsigned short)vreg2[j] << 16);
            int d1 = w * 16 + 8 + j;
            Vt32[d1 * 64 + (l ^ ((d1 & 7) << 2))] =
                (unsigned)(unsigned short)vreg1[j] | ((unsigned)(unsigned short)vreg3[j] << 16);
        }
    };

    // ---- prologue ----
    loadK(0); loadV(0);
    writeK(); writeV();
    __syncthreads();

    for (int kt = 0; kt < S_ / 128; ++kt) {
        if (kt < S_ / 128 - 1) { loadK(kt + 1); loadV(kt + 1); }   // prefetch to regs

        #pragma unroll
        for (int h = 0; h < 2; ++h) {       // two 64-col halves
            // ---- S = Q K^T for this half : 16 MFMA ----
            f32x4 sacc[2][4];
            #pragma unroll
            for (int qt = 0; qt < 2; ++qt)
                #pragma unroll
                for (int kj = 0; kj < 4; ++kj) sacc[qt][kj] = (f32x4){0.f, 0.f, 0.f, 0.f};

            #pragma unroll
            for (int ks = 0; ks < 2; ++ks) {
                bf16x8 kf[4];
                #pragma unroll
                for (int kj = 0; kj < 4; ++kj) {
                    int r = (h * 4 + kj) * 16 + l15;
                    kf[kj] = *reinterpret_cast<const bf16x8*>(
                        &Ks[r * 64 + (((ks * 4 + g) ^ (r & 7)) << 3)]);
                }
                #pragma unroll
                for (int qt = 0; qt < 2; ++qt)
                    #pragma unroll
                    for (int kj = 0; kj < 4; ++kj)
                        sacc[qt][kj] = __builtin_amdgcn_mfma_f32_16x16x32_bf16(
                            qf[qt][ks], kf[kj], sacc[qt][kj], 0, 0, 0);
            }

            // ---- no-max softmax on this half + P store ----
            #pragma unroll
            for (int qt = 0; qt < 2; ++qt) {
                #pragma unroll
                for (int reg = 0; reg < 4; ++reg) {
                    int q = qt * 16 + g * 4 + reg;
                    short* pr = Pw + q * 64;
                    int qs = q & 7;
                    float psum = 0.f;
                    #pragma unroll
                    for (int kj = 0; kj < 4; ++kj) {
                        float p = exp2f(sacc[qt][kj][reg] * 0.18033688f);
                        psum += p;
                        int c = kj * 16 + l15;
                        pr[(((c >> 3) ^ qs) << 3) | (c & 7)] =
                            (short)((__float_as_uint(p) + 0x8000u) >> 16);
                    }
                    lsum[qt][reg] += psum;
                }
            }

            // ---- O += P V for this half : 16 MFMA ----
            #pragma unroll
            for (int s = 0; s < 2; ++s) {
                int kse = h * 2 + s;
                bf16x8 pf[2], vf[4];
                #pragma unroll
                for (int qt = 0; qt < 2; ++qt) {
                    int q = qt * 16 + l15;
                    pf[qt] = *reinterpret_cast<const bf16x8*>(
                        &Pw[q * 64 + (((s * 4 + g) ^ (q & 7)) << 3)]);
                }
                #pragma unroll
                for (int dt = 0; dt < 4; ++dt) {
                    int d = dt * 16 + l15;
                    vf[dt] = *reinterpret_cast<const bf16x8*>(
                        &Vt32[d * 64 + ((kse * 16 + g * 4) ^ ((d & 7) << 2))]);
                }
                #pragma unroll
                for (int qt = 0; qt < 2; ++qt)
                    #pragma unroll
                    for (int dt = 0; dt < 4; ++dt)
                        oacc[qt][dt] = __builtin_amdgcn_mfma_f32_16x16x32_bf16(
                            pf[qt], vf[dt], oacc[qt][dt], 0, 0, 0);
            }
        }

        __syncthreads();                   // all waves done with Ks/Vt
        if (kt < S_ / 128 - 1) { writeK(); writeV(); }
        __syncthreads();                   // next tile visible
    }

    // ---- epilogue: normalize, transpose via Pw, coalesced bf16x8 stores ----
    #pragma unroll
    for (int qt = 0; qt < 2; ++qt)
        #pragma unroll
        for (int reg = 0; reg < 4; ++reg) {
            float s = lsum[qt][reg];
            s += __shfl_xor(s, 1); s += __shfl_xor(s, 2);
            s += __shfl_xor(s, 4); s += __shfl_xor(s, 8);
            float inv = 1.0f / s;
            int q = qt * 16 + g * 4 + reg;
            int qs = q & 7;
            #pragma unroll
            for (int dt = 0; dt < 4; ++dt) {
                int d = dt * 16 + l15;
                Pw[q * 64 + ((((d >> 3) ^ qs) << 3) | (d & 7))] =
                    (short)f2bf(oacc[qt][dt][reg] * inv);
            }
        }
    // wave-private: no barrier needed; compiler inserts lgkm waits
    unsigned short* ao = attnb + ((size_t)bb * S_ + q0 + w * 32) * D_ + hh * DK_;
    #pragma unroll
    for (int i = 0; i < 4; ++i) {
        int idx = l + i * 64;
        int rr = idx >> 3, cc = idx & 7;
        bf16x8 vv = *reinterpret_cast<const bf16x8*>(
            &Pw[rr * 64 + ((cc ^ (rr & 7)) << 3)]);
        *reinterpret_cast<bf16x8*>(ao + (size_t)rr * D_ + cc * 8) = vv;
    }
}

// ---------------------------------------------------------------------------
// bf16 GEMM, 64x128 tile, dbuf global_load_lds, ONE barrier per K-step.
// grid (M/64, 768/128) = 768 blocks, 48 KB LDS -> 3 blocks/CU.
// ---------------------------------------------------------------------------
template<int KDIM>
__global__ __launch_bounds__(256, 3)
void gemm_bf16(const unsigned short* __restrict__ A, const unsigned short* __restrict__ Bw,
               const float* __restrict__ res, float* __restrict__ out)
{
    __shared__ __align__(16) short As[2][64 * 64];    // 16 KB
    __shared__ __align__(16) short Bs[2][128 * 64];   // 32 KB

    const int tid = threadIdx.x;
    const int w = tid >> 6, l = tid & 63, g = l >> 4, l15 = l & 15;
    const int wr = w >> 1, wc = w & 1;
    const int m0 = blockIdx.x * 64, n0 = blockIdx.y * 128;

    auto stage = [&](int k0, int buf) {
        #pragma unroll
        for (int it = 0; it < 2; ++it) {           // A: 512 chunks
            int c = tid + it * 256;
            int r = c >> 3, b = c & 7;
            const unsigned short* ga = A + (size_t)(m0 + r) * KDIM + k0 + ((b ^ (r & 7)) << 3);
            __builtin_amdgcn_global_load_lds((const AS1 void*)ga,
                (AS3 void*)(&As[buf][0] + ((it * 256 + w * 64) << 3)), 16, 0, 0);
        }
        #pragma unroll
        for (int it = 0; it < 4; ++it) {           // B: 1024 chunks
            int c = tid + it * 256;
            int r = c >> 3, b = c & 7;
            const unsigned short* gb = Bw + (size_t)(n0 + r) * KDIM + k0 + ((b ^ (r & 7)) << 3);
            __builtin_amdgcn_global_load_lds((const AS1 void*)gb,
                (AS3 void*)(&Bs[buf][0] + ((it * 256 + w * 64) << 3)), 16, 0, 0);
        }
    };

    f32x4 acc[2][4];
    #pragma unroll
    for (int i = 0; i < 2; ++i)
        #pragma unroll
        for (int j = 0; j < 4; ++j) acc[i][j] = (f32x4){0.f, 0.f, 0.f, 0.f};

    stage(0, 0);
    __syncthreads();                       // tile 0 ready

    const int NS = KDIM / 64;
    int cur = 0;
    for (int s = 0; s < NS; ++s) {
        if (s + 1 < NS) stage((s + 1) * 64, cur ^ 1);   // prefetch (lands during MFMA)

        #pragma unroll
        for (int ks = 0; ks < 2; ++ks) {
            bf16x8 af[2], bf[4];
            #pragma unroll
            for (int mt = 0; mt < 2; ++mt) {
                int r = wr * 32 + mt * 16 + l15;
                af[mt] = *reinterpret_cast<const bf16x8*>(
                    &As[cur][r * 64 + (((ks * 4 + g) ^ (r & 7)) << 3)]);
            }
            #pragma unroll
            for (int nt = 0; nt < 4; ++nt) {
                int cc = wc * 64 + nt * 16 + l15;
                bf[nt] = *reinterpret_cast<const bf16x8*>(
                    &Bs[cur][cc * 64 + (((ks * 4 + g) ^ (cc & 7)) << 3)]);
            }
            #pragma unroll
            for (int mt = 0; mt < 2; ++mt)
                #pragma unroll
                for (int nt = 0; nt < 4; ++nt)
                    acc[mt][nt] = __builtin_amdgcn_mfma_f32_16x16x32_bf16(
                        af[mt], bf[nt], acc[mt][nt], 0, 0, 0);
        }

        __syncthreads();   // waves done reading cur; next-tile gll drained (landed)
        cur ^= 1;
    }

    #pragma unroll
    for (int mt = 0; mt < 2; ++mt)
        #pragma unroll
        for (int reg = 0; reg < 4; ++reg) {
            size_t row = (size_t)m0 + wr * 32 + mt * 16 + g * 4 + reg;
            #pragma unroll
            for (int nt = 0; nt < 4; ++nt) {
                int col = n0 + wc * 64 + nt * 16 + l15;
                out[row * D_ + col] = acc[mt][nt][reg] + res[row * D_ + col];
            }
        }
}

// ---------------------------------------------------------------------------
// T-build: Tb[row][c] = relu(sum_q cos(h[row][q])cos(theta[q]) * w1[c][q]).
// grid M/16, block 256. w1s XOR-swizzled.
// ---------------------------------------------------------------------------
__global__ __launch_bounds__(256, 2)
void tbuild(const float* __restrict__ h, const float* __restrict__ theta,
            const float* __restrict__ w1, unsigned short* __restrict__ Tb)
{
    __shared__ __align__(16) short w1s[FFN_ * NQ_];    // 48 KB

    const int tid = threadIdx.x;
    const int w = tid >> 6, l = tid & 63;

    #pragma unroll
    for (int it = 0; it < 12; ++it) {
        int c = tid + it * 256;                 // col chunk 0..3071
        float4 f0 = *reinterpret_cast<const float4*>(w1 + (size_t)c * 8);
        float4 f1 = *reinterpret_cast<const float4*>(w1 + (size_t)c * 8 + 4);
        *reinterpret_cast<bf16x8*>(&w1s[(c ^ ((c >> 3) & 7)) * 8]) = pack8(f0, f1);
    }
    __syncthreads();

    float cth[NQ_];
    #pragma unroll
    for (int q = 0; q < NQ_; ++q) cth[q] = cosf(theta[q]);

    #pragma unroll
    for (int rr = 0; rr < 4; ++rr) {
        int row = blockIdx.x * 16 + w * 4 + rr;
        const float* hp = h + (size_t)row * D_;
        float meas[NQ_];
        #pragma unroll
        for (int q = 0; q < NQ_; ++q) meas[q] = cosf(hp[q]) * cth[q];
        unsigned short* outp = Tb + (size_t)row * FFN_;
        #pragma unroll
        for (int itc = 0; itc < 6; ++itc) {
            int cbase = itc * 512 + l * 8;
            bf16x8 tv;
            #pragma unroll
            for (int cc = 0; cc < 8; ++cc) {
                bf16x8 wv = *reinterpret_cast<const bf16x8*>(
                    &w1s[((cbase + cc) ^ (l & 7)) * 8]);
                float t = 0.f;
                #pragma unroll
                for (int q = 0; q < NQ_; ++q)
                    t = fmaf(meas[q], bf2f((unsigned short)wv[q]), t);
                tv[cc] = (short)f2bf(fmaxf(t, 0.f));
            }
            *reinterpret_cast<bf16x8*>(&outp[cbase]) = tv;
        }
    }
}

// ---------------------------------------------------------------------------
// LayerNorm. One wave per row. grid M/4, block 256. Safe in-place.
// ---------------------------------------------------------------------------
__global__ __launch_bounds__(256, 4)
void ln_kernel(const float* __restrict__ in, const float* __restrict__ g,
               const float* __restrict__ bt, float* __restrict__ out)
{
    const int wave = threadIdx.x >> 6, lane = threadIdx.x & 63;
    const size_t row = (size_t)blockIdx.x * 4 + wave;
    const float* p = in + row * D_;
    float v[12];
    float sum = 0.f;
    #pragma unroll
    for (int c = 0; c < 3; ++c) {
        float4 f = *reinterpret_cast<const float4*>(p + (c * 64 + lane) * 4);
        v[c*4+0] = f.x; v[c*4+1] = f.y; v[c*4+2] = f.z; v[c*4+3] = f.w;
        sum += (f.x + f.y) + (f.z + f.w);
    }
    #pragma unroll
    for (int msk = 1; msk < 64; msk <<= 1) sum += __shfl_xor(sum, msk);
    const float mu = sum * (1.0f / 768.0f);
    float vs = 0.f;
    #pragma unroll
    for (int k = 0; k < 12; ++k) { float d = v[k] - mu; vs = fmaf(d, d, vs); }
    #pragma unroll
    for (int msk = 1; msk < 64; msk <<= 1) vs += __shfl_xor(vs, msk);
    const float rstd = rsqrtf(vs * (1.0f / 768.0f) + 1e-5f);
    float* po = out + row * D_;
    #pragma unroll
    for (int c = 0; c < 3; ++c) {
        const int base = (c * 64 + lane) * 4;
        float4 gg = *reinterpret_cast<const float4*>(g + base);
        float4 bb2 = *reinterpret_cast<const float4*>(bt + base);
        float4 r;
        r.x = (v[c*4+0] - mu) * rstd * gg.x + bb2.x;
        r.y = (v[c*4+1] - mu) * rstd * gg.y + bb2.y;
        r.z = (v[c*4+2] - mu) * rstd * gg.z + bb2.z;
        r.w = (v[c*4+3] - mu) * rstd * gg.w + bb2.w;
        *reinterpret_cast<float4*>(po + base) = r;
    }
}

// ---------------------------------------------------------------------------
extern "C" void kernel_launch(void* const* d_in, const int* in_sizes, int n_in,
                              void* d_out, int out_size, void* d_ws, size_t ws_size,
                              hipStream_t stream)
{
    const float* x   = (const float*)d_in[0];
    const float* cw  = (const float*)d_in[1];
    const float* th  = (const float*)d_in[2];
    const float* w1  = (const float*)d_in[3];
    const float* w2  = (const float*)d_in[4];
    const float* g1  = (const float*)d_in[5];
    const float* b1  = (const float*)d_in[6];
    const float* g2  = (const float*)d_in[7];
    const float* b2  = (const float*)d_in[8];
    float* out = (float*)d_out;

    const size_t HB  = 25165824;   // region0: xb (12.6MB) then hbuf f32 (25.2MB)
    const size_t TBB = 50331648;   // region1: attnb (12.6MB) then Tb (50.3MB)
    const size_t CWB = 1179648;

    char* wsc = (char*)d_ws;
    unsigned short* xbuf  = (unsigned short*)wsc;          // dead after attn
    float*          hbuf  = (float*)wsc;                   // live from LN1
    unsigned short* attnb = (unsigned short*)(wsc + HB);   // dead before tbuild
    unsigned short* Tb    = (unsigned short*)(wsc + HB);
    unsigned short* cwb   = (unsigned short*)(wsc + HB + TBB);
    unsigned short* w2b   = (unsigned short*)(wsc + HB + TBB + CWB);

    convert_all    <<<dim3((XCH + CWCH + W2CH) / 256), 256, 0, stream>>>(x, cw, w2, xbuf, cwb, w2b);
    attn_mfma      <<<dim3(16 * H_ * B_), 256, 0, stream>>>(xbuf, attnb);
    gemm_bf16<D_>  <<<dim3(M_ / 64, D_ / 128), 256, 0, stream>>>(attnb, cwb, x, out);
    ln_kernel      <<<dim3(M_ / 4), 256, 0, stream>>>(out, g1, b1, hbuf);
    tbuild         <<<dim3(M_ / 16), 256, 0, stream>>>(hbuf, th, w1, Tb);
    gemm_bf16<FFN_><<<dim3(M_ / 64, D_ / 128), 256, 0, stream>>>(Tb, w2b, hbuf, out);
    ln_kernel      <<<dim3(M_ / 4), 256, 0, stream>>>(out, g2, b2, out);
}

// Round 9
// 538.582 us; speedup vs baseline: 1.2488x; 1.2488x over previous
//
#include <hip/hip_runtime.h>
#include <math.h>

// ---------------------------------------------------------------------------
// TransformerBlockQuantum — round 9
//  REVERT attn to round-7 structure (r8's reg-staged K/V spilled: 84 VGPR,
//  1.2 GB scratch traffic/dispatch) + coalesced bf16x8 epilogue via P-LDS.
//  GEMMs: r7 single-buffer 64x128 form. Everything else unchanged.
// ---------------------------------------------------------------------------

#define B_    4
#define S_    2048
#define D_    768
#define H_    12
#define DK_   64
#define FFN_  3072
#define NQ_   8
#define M_    (B_ * S_)          // 8192 rows

#define AS1 __attribute__((address_space(1)))
#define AS3 __attribute__((address_space(3)))

typedef __attribute__((ext_vector_type(8))) short bf16x8;   // 8 bf16 = 4 VGPR
typedef __attribute__((ext_vector_type(4))) float f32x4;

static __device__ __forceinline__ unsigned short f2bf(float f) {
    unsigned u = __float_as_uint(f);
    unsigned r = (u + 0x7FFFu + ((u >> 16) & 1u)) >> 16;   // RNE
    return (unsigned short)r;
}
static __device__ __forceinline__ float bf2f(unsigned short h) {
    return __uint_as_float((unsigned)h << 16);
}
static __device__ __forceinline__ bf16x8 pack8(float4 a, float4 b) {
    bf16x8 r;
    r[0] = (short)f2bf(a.x); r[1] = (short)f2bf(a.y);
    r[2] = (short)f2bf(a.z); r[3] = (short)f2bf(a.w);
    r[4] = (short)f2bf(b.x); r[5] = (short)f2bf(b.y);
    r[6] = (short)f2bf(b.z); r[7] = (short)f2bf(b.w);
    return r;
}

// ---------------------------------------------------------------------------
// Conversion: x (6291456), cw (589824), w2 (2359296) f32 -> bf16.
// ---------------------------------------------------------------------------
#define XCH  786432   // 6291456/8
#define CWCH 73728    // 589824/8
#define W2CH 294912   // 2359296/8
__global__ void convert_all(const float* __restrict__ x, const float* __restrict__ cw,
                            const float* __restrict__ w2,
                            unsigned short* __restrict__ xb, unsigned short* __restrict__ cwb,
                            unsigned short* __restrict__ w2b)
{
    int idx = blockIdx.x * 256 + threadIdx.x;     // chunk of 8 floats
    const float* src; unsigned short* dst; int c;
    if (idx < XCH)              { src = x;  dst = xb;  c = idx; }
    else if (idx < XCH + CWCH)  { src = cw; dst = cwb; c = idx - XCH; }
    else { c = idx - XCH - CWCH; if (c >= W2CH) return; src = w2; dst = w2b; }
    float4 f0 = *reinterpret_cast<const float4*>(src + (size_t)c * 8);
    float4 f1 = *reinterpret_cast<const float4*>(src + (size_t)c * 8 + 4);
    *reinterpret_cast<bf16x8*>(dst + (size_t)c * 8) = pack8(f0, f1);
}

// ---------------------------------------------------------------------------
// Flash attention (round-7 structure, proven 192 µs / no spill).
// grid 768 (XCD-swizzled), block 256 (4 waves), 80 KB LDS, 2 blocks/CU.
// K via dbuf global_load_lds; V short-lived reg->LDS; no-max softmax.
// NEW vs r7: coalesced bf16x8 epilogue staged through the P buffer.
// ---------------------------------------------------------------------------
__global__ __launch_bounds__(256, 2)
void attn_mfma(const unsigned short* __restrict__ xb, unsigned short* __restrict__ attnb)
{
    __shared__ __align__(16) short    Ks[2][128 * 64];  // 32 KB (dbuf)
    __shared__ __align__(16) unsigned Vt32[64 * 64];    // 16 KB
    __shared__ __align__(16) short    Ps[4][32 * 128];  // 32 KB (per-wave)

    const int tid = threadIdx.x;
    const int w   = tid >> 6;
    const int l   = tid & 63;
    const int g   = l >> 4;
    const int l15 = l & 15;

    // XCD-aware decode: blocks sharing (b,h) K/V stream share flat%8 residue.
    const int flat = blockIdx.x;
    const int rx = flat & 7;
    const int t  = flat >> 3;              // 0..95
    const int gq = t & 15;                 // q-tile
    const int G  = (t >> 4) * 8 + rx;      // 0..47 group (b*12+h)
    const int hh = G % 12, bb = G / 12;
    const int q0 = gq * 128;

    const unsigned short* xh = xb + ((size_t)bb * S_) * D_ + hh * DK_;

    // ---- hoist Q fragments (bf16, direct) ----
    bf16x8 qf[2][2];
    {
        const unsigned short* xq = xh + (size_t)(q0 + w * 32) * D_;
        #pragma unroll
        for (int qt = 0; qt < 2; ++qt)
            #pragma unroll
            for (int ks = 0; ks < 2; ++ks)
                qf[qt][ks] = *reinterpret_cast<const bf16x8*>(
                    xq + (size_t)(qt * 16 + l15) * D_ + ks * 32 + g * 8);
    }

    f32x4 oacc[2][4];
    float lsum[2][4];
    #pragma unroll
    for (int qt = 0; qt < 2; ++qt)
        #pragma unroll
        for (int i = 0; i < 4; ++i) {
            oacc[qt][i] = (f32x4){0.f, 0.f, 0.f, 0.f};
            lsum[qt][i] = 0.f;
        }

    short* Pw = Ps[w];
    bf16x8 vh0, vh1, vh2, vh3;             // V hold regs (2 rows x 16 d)
    const int kvp = tid & 63, dg = tid >> 6;

    // ---- staging helpers ----
    auto stageK = [&](int kt, int buf) {
        const unsigned short* xk = xh + (size_t)(kt * 128) * D_;
        #pragma unroll
        for (int it = 0; it < 4; ++it) {
            int c = tid + it * 256;
            int r = c >> 3, b2 = c & 7;
            const unsigned short* gsrc = xk + (size_t)r * D_ + ((b2 ^ (r & 7)) << 3);
            __builtin_amdgcn_global_load_lds(
                (const AS1 void*)gsrc,
                (AS3 void*)(&Ks[buf][0] + ((it * 256 + w * 64) << 3)), 16, 0, 0);
        }
    };
    auto loadV = [&](int kt) {
        const unsigned short* ra = xh + (size_t)(kt * 128 + 2 * kvp) * D_ + dg * 16;
        vh0 = *reinterpret_cast<const bf16x8*>(ra);
        vh1 = *reinterpret_cast<const bf16x8*>(ra + 8);
        vh2 = *reinterpret_cast<const bf16x8*>(ra + D_);
        vh3 = *reinterpret_cast<const bf16x8*>(ra + D_ + 8);
    };
    auto writeV = [&]() {
        #pragma unroll
        for (int j = 0; j < 8; ++j) {
            int d0 = dg * 16 + j;
            Vt32[d0 * 64 + (kvp ^ ((d0 & 7) << 2))] =
                (unsigned)(unsigned short)vh0[j] | ((unsigned)(unsigned short)vh2[j] << 16);
            int d1 = dg * 16 + 8 + j;
            Vt32[d1 * 64 + (kvp ^ ((d1 & 7) << 2))] =
                (unsigned)(unsigned short)vh1[j] | ((unsigned)(unsigned short)vh3[j] << 16);
        }
    };

    // ---- prologue: tile 0 ----
    stageK(0, 0);
    loadV(0);
    writeV();                 // compiler waits vmcnt for vh
    __syncthreads();          // drains K gll too

    for (int kt = 0; kt < S_ / 128; ++kt) {
        const int cur = kt & 1;
        if (kt < S_ / 128 - 1) {           // prefetch next tile (hides under compute)
            stageK(kt + 1, cur ^ 1);
            loadV(kt + 1);
        }

        // ---- S = Q K^T : 32 MFMA ----
        f32x4 sacc[2][8];
        #pragma unroll
        for (int qt = 0; qt < 2; ++qt)
            #pragma unroll
            for (int kj = 0; kj < 8; ++kj) sacc[qt][kj] = (f32x4){0.f, 0.f, 0.f, 0.f};

        #pragma unroll
        for (int ks = 0; ks < 2; ++ks) {
            bf16x8 kf[8];
            #pragma unroll
            for (int kj = 0; kj < 8; ++kj) {
                int r = kj * 16 + l15;
                kf[kj] = *reinterpret_cast<const bf16x8*>(
                    &Ks[cur][r * 64 + (((ks * 4 + g) ^ (r & 7)) << 3)]);
            }
            #pragma unroll
            for (int qt = 0; qt < 2; ++qt)
                #pragma unroll
                for (int kj = 0; kj < 8; ++kj)
                    sacc[qt][kj] = __builtin_amdgcn_mfma_f32_16x16x32_bf16(
                        qf[qt][ks], kf[kj], sacc[qt][kj], 0, 0, 0);
        }

        // ---- no-max softmax: p = exp2(s * 0.125*log2e); per-lane l partials ----
        #pragma unroll
        for (int qt = 0; qt < 2; ++qt) {
            #pragma unroll
            for (int reg = 0; reg < 4; ++reg) {
                int q = qt * 16 + g * 4 + reg;
                short* pr = Pw + q * 128;
                int qs = q & 7;
                float psum = 0.f;
                #pragma unroll
                for (int kj = 0; kj < 8; ++kj) {
                    float p = exp2f(sacc[qt][kj][reg] * 0.18033688f);
                    psum += p;
                    int c = kj * 16 + l15;
                    pr[(((c >> 3) ^ qs) << 3) | (c & 7)] =
                        (short)((__float_as_uint(p) + 0x8000u) >> 16);
                }
                lsum[qt][reg] += psum;
            }
        }

        // ---- O += P V : 32 MFMA ----
        #pragma unroll
        for (int ks = 0; ks < 4; ++ks) {
            bf16x8 pf[2], vf[4];
            #pragma unroll
            for (int qt = 0; qt < 2; ++qt) {
                int q = qt * 16 + l15;
                pf[qt] = *reinterpret_cast<const bf16x8*>(
                    &Pw[q * 128 + (((ks * 4 + g) ^ (q & 7)) << 3)]);
            }
            #pragma unroll
            for (int dt = 0; dt < 4; ++dt) {
                int d = dt * 16 + l15;
                vf[dt] = *reinterpret_cast<const bf16x8*>(
                    &Vt32[d * 64 + ((ks * 16 + g * 4) ^ ((d & 7) << 2))]);
            }
            #pragma unroll
            for (int qt = 0; qt < 2; ++qt)
                #pragma unroll
                for (int dt = 0; dt < 4; ++dt)
                    oacc[qt][dt] = __builtin_amdgcn_mfma_f32_16x16x32_bf16(
                        pf[qt], vf[dt], oacc[qt][dt], 0, 0, 0);
        }

        __syncthreads();                   // all waves done reading Vt / Ks[cur]
        if (kt < S_ / 128 - 1) writeV();   // vmcnt waited here by compiler
        __syncthreads();                   // Vt + Ks[cur^1] ready
    }

    // ---- epilogue v2: normalize -> wave-private P-LDS -> coalesced bf16x8 ----
    #pragma unroll
    for (int qt = 0; qt < 2; ++qt)
        #pragma unroll
        for (int reg = 0; reg < 4; ++reg) {
            float s = lsum[qt][reg];
            s += __shfl_xor(s, 1); s += __shfl_xor(s, 2);
            s += __shfl_xor(s, 4); s += __shfl_xor(s, 8);
            float inv = 1.0f / s;
            int q = qt * 16 + g * 4 + reg;
            int qs = q & 7;
            #pragma unroll
            for (int dt = 0; dt < 4; ++dt) {
                int d = dt * 16 + l15;                    // 16 lanes -> 16 cols of row q
                Pw[q * 64 + ((((d >> 3) ^ qs) << 3) | (d & 7))] =
                    (short)f2bf(oacc[qt][dt][reg] * inv);
            }
        }
    // wave-private buffer: no cross-wave barrier needed (compiler inserts
    // lgkmcnt waits for the same-address RAW within the wave).
    unsigned short* ao = attnb + ((size_t)bb * S_ + q0 + w * 32) * D_ + hh * DK_;
    #pragma unroll
    for (int i = 0; i < 4; ++i) {
        int idx = l + i * 64;                 // 0..255 -> (row 0..31, chunk 0..7)
        int rr = idx >> 3, cc = idx & 7;
        bf16x8 vv = *reinterpret_cast<const bf16x8*>(
            &Pw[rr * 64 + ((cc ^ (rr & 7)) << 3)]);
        *reinterpret_cast<bf16x8*>(ao + (size_t)rr * D_ + cc * 8) = vv;
    }
}

// ---------------------------------------------------------------------------
// bf16 GEMM (round-7 form), 64x128 tile, single-buffer global_load_lds.
// grid (M/64, 768/128) = 768 blocks, 24 KB LDS -> 3 blocks/CU.
// ---------------------------------------------------------------------------
template<int KDIM>
__global__ __launch_bounds__(256, 3)
void gemm_bf16(const unsigned short* __restrict__ A, const unsigned short* __restrict__ Bw,
               const float* __restrict__ res, float* __restrict__ out)
{
    __shared__ __align__(16) short As[64 * 64];    // 8 KB
    __shared__ __align__(16) short Bs[128 * 64];   // 16 KB

    const int tid = threadIdx.x;
    const int w = tid >> 6, l = tid & 63, g = l >> 4, l15 = l & 15;
    const int wr = w >> 1, wc = w & 1;
    const int m0 = blockIdx.x * 64, n0 = blockIdx.y * 128;

    f32x4 acc[2][4];
    #pragma unroll
    for (int i = 0; i < 2; ++i)
        #pragma unroll
        for (int j = 0; j < 4; ++j) acc[i][j] = (f32x4){0.f, 0.f, 0.f, 0.f};

    for (int k0 = 0; k0 < KDIM; k0 += 64) {
        __syncthreads();
        #pragma unroll
        for (int it = 0; it < 2; ++it) {           // A: 512 chunks
            int c = tid + it * 256;
            int r = c >> 3, b = c & 7;
            const unsigned short* ga = A + (size_t)(m0 + r) * KDIM + k0 + ((b ^ (r & 7)) << 3);
            __builtin_amdgcn_global_load_lds((const AS1 void*)ga,
                (AS3 void*)(As + ((it * 256 + w * 64) << 3)), 16, 0, 0);
        }
        #pragma unroll
        for (int it = 0; it < 4; ++it) {           // B: 1024 chunks
            int c = tid + it * 256;
            int r = c >> 3, b = c & 7;
            const unsigned short* gb = Bw + (size_t)(n0 + r) * KDIM + k0 + ((b ^ (r & 7)) << 3);
            __builtin_amdgcn_global_load_lds((const AS1 void*)gb,
                (AS3 void*)(Bs + ((it * 256 + w * 64) << 3)), 16, 0, 0);
        }
        __syncthreads();

        #pragma unroll
        for (int ks = 0; ks < 2; ++ks) {
            bf16x8 af[2], bf[4];
            #pragma unroll
            for (int mt = 0; mt < 2; ++mt) {
                int r = wr * 32 + mt * 16 + l15;
                af[mt] = *reinterpret_cast<const bf16x8*>(
                    &As[r * 64 + (((ks * 4 + g) ^ (r & 7)) << 3)]);
            }
            #pragma unroll
            for (int nt = 0; nt < 4; ++nt) {
                int cc = wc * 64 + nt * 16 + l15;
                bf[nt] = *reinterpret_cast<const bf16x8*>(
                    &Bs[cc * 64 + (((ks * 4 + g) ^ (cc & 7)) << 3)]);
            }
            #pragma unroll
            for (int mt = 0; mt < 2; ++mt)
                #pragma unroll
                for (int nt = 0; nt < 4; ++nt)
                    acc[mt][nt] = __builtin_amdgcn_mfma_f32_16x16x32_bf16(
                        af[mt], bf[nt], acc[mt][nt], 0, 0, 0);
        }
    }

    #pragma unroll
    for (int mt = 0; mt < 2; ++mt)
        #pragma unroll
        for (int reg = 0; reg < 4; ++reg) {
            size_t row = (size_t)m0 + wr * 32 + mt * 16 + g * 4 + reg;
            #pragma unroll
            for (int nt = 0; nt < 4; ++nt) {
                int col = n0 + wc * 64 + nt * 16 + l15;
                out[row * D_ + col] = acc[mt][nt][reg] + res[row * D_ + col];
            }
        }
}

// ---------------------------------------------------------------------------
// T-build: Tb[row][c] = relu(sum_q cos(h[row][q])cos(theta[q]) * w1[c][q]).
// grid M/16, block 256. w1s XOR-swizzled.
// ---------------------------------------------------------------------------
__global__ __launch_bounds__(256, 2)
void tbuild(const float* __restrict__ h, const float* __restrict__ theta,
            const float* __restrict__ w1, unsigned short* __restrict__ Tb)
{
    __shared__ __align__(16) short w1s[FFN_ * NQ_];    // 48 KB

    const int tid = threadIdx.x;
    const int w = tid >> 6, l = tid & 63;

    #pragma unroll
    for (int it = 0; it < 12; ++it) {
        int c = tid + it * 256;                 // col chunk 0..3071
        float4 f0 = *reinterpret_cast<const float4*>(w1 + (size_t)c * 8);
        float4 f1 = *reinterpret_cast<const float4*>(w1 + (size_t)c * 8 + 4);
        *reinterpret_cast<bf16x8*>(&w1s[(c ^ ((c >> 3) & 7)) * 8]) = pack8(f0, f1);
    }
    __syncthreads();

    float cth[NQ_];
    #pragma unroll
    for (int q = 0; q < NQ_; ++q) cth[q] = cosf(theta[q]);

    #pragma unroll
    for (int rr = 0; rr < 4; ++rr) {
        int row = blockIdx.x * 16 + w * 4 + rr;
        const float* hp = h + (size_t)row * D_;
        float meas[NQ_];
        #pragma unroll
        for (int q = 0; q < NQ_; ++q) meas[q] = cosf(hp[q]) * cth[q];
        unsigned short* outp = Tb + (size_t)row * FFN_;
        #pragma unroll
        for (int itc = 0; itc < 6; ++itc) {
            int cbase = itc * 512 + l * 8;
            bf16x8 tv;
            #pragma unroll
            for (int cc = 0; cc < 8; ++cc) {
                bf16x8 wv = *reinterpret_cast<const bf16x8*>(
                    &w1s[((cbase + cc) ^ (l & 7)) * 8]);
                float t = 0.f;
                #pragma unroll
                for (int q = 0; q < NQ_; ++q)
                    t = fmaf(meas[q], bf2f((unsigned short)wv[q]), t);
                tv[cc] = (short)f2bf(fmaxf(t, 0.f));
            }
            *reinterpret_cast<bf16x8*>(&outp[cbase]) = tv;
        }
    }
}

// ---------------------------------------------------------------------------
// LayerNorm. One wave per row. grid M/4, block 256. Safe in-place.
// ---------------------------------------------------------------------------
__global__ __launch_bounds__(256, 4)
void ln_kernel(const float* __restrict__ in, const float* __restrict__ g,
               const float* __restrict__ bt, float* __restrict__ out)
{
    const int wave = threadIdx.x >> 6, lane = threadIdx.x & 63;
    const size_t row = (size_t)blockIdx.x * 4 + wave;
    const float* p = in + row * D_;
    float v[12];
    float sum = 0.f;
    #pragma unroll
    for (int c = 0; c < 3; ++c) {
        float4 f = *reinterpret_cast<const float4*>(p + (c * 64 + lane) * 4);
        v[c*4+0] = f.x; v[c*4+1] = f.y; v[c*4+2] = f.z; v[c*4+3] = f.w;
        sum += (f.x + f.y) + (f.z + f.w);
    }
    #pragma unroll
    for (int msk = 1; msk < 64; msk <<= 1) sum += __shfl_xor(sum, msk);
    const float mu = sum * (1.0f / 768.0f);
    float vs = 0.f;
    #pragma unroll
    for (int k = 0; k < 12; ++k) { float d = v[k] - mu; vs = fmaf(d, d, vs); }
    #pragma unroll
    for (int msk = 1; msk < 64; msk <<= 1) vs += __shfl_xor(vs, msk);
    const float rstd = rsqrtf(vs * (1.0f / 768.0f) + 1e-5f);
    float* po = out + row * D_;
    #pragma unroll
    for (int c = 0; c < 3; ++c) {
        const int base = (c * 64 + lane) * 4;
        float4 gg = *reinterpret_cast<const float4*>(g + base);
        float4 bb2 = *reinterpret_cast<const float4*>(bt + base);
        float4 r;
        r.x = (v[c*4+0] - mu) * rstd * gg.x + bb2.x;
        r.y = (v[c*4+1] - mu) * rstd * gg.y + bb2.y;
        r.z = (v[c*4+2] - mu) * rstd * gg.z + bb2.z;
        r.w = (v[c*4+3] - mu) * rstd * gg.w + bb2.w;
        *reinterpret_cast<float4*>(po + base) = r;
    }
}

// ---------------------------------------------------------------------------
extern "C" void kernel_launch(void* const* d_in, const int* in_sizes, int n_in,
                              void* d_out, int out_size, void* d_ws, size_t ws_size,
                              hipStream_t stream)
{
    const float* x   = (const float*)d_in[0];
    const float* cw  = (const float*)d_in[1];
    const float* th  = (const float*)d_in[2];
    const float* w1  = (const float*)d_in[3];
    const float* w2  = (const float*)d_in[4];
    const float* g1  = (const float*)d_in[5];
    const float* b1  = (const float*)d_in[6];
    const float* g2  = (const float*)d_in[7];
    const float* b2  = (const float*)d_in[8];
    float* out = (float*)d_out;

    const size_t HB  = 25165824;   // region0: xb (12.6MB) then hbuf f32 (25.2MB)
    const size_t TBB = 50331648;   // region1: attnb (12.6MB) then Tb (50.3MB)
    const size_t CWB = 1179648;

    char* wsc = (char*)d_ws;
    unsigned short* xbuf  = (unsigned short*)wsc;          // dead after attn
    float*          hbuf  = (float*)wsc;                   // live from LN1
    unsigned short* attnb = (unsigned short*)(wsc + HB);   // dead before tbuild
    unsigned short* Tb    = (unsigned short*)(wsc + HB);
    unsigned short* cwb   = (unsigned short*)(wsc + HB + TBB);
    unsigned short* w2b   = (unsigned short*)(wsc + HB + TBB + CWB);

    convert_all    <<<dim3((XCH + CWCH + W2CH) / 256), 256, 0, stream>>>(x, cw, w2, xbuf, cwb, w2b);
    attn_mfma      <<<dim3(16 * H_ * B_), 256, 0, stream>>>(xbuf, attnb);
    gemm_bf16<D_>  <<<dim3(M_ / 64, D_ / 128), 256, 0, stream>>>(attnb, cwb, x, out);
    ln_kernel      <<<dim3(M_ / 4), 256, 0, stream>>>(out, g1, b1, hbuf);
    tbuild         <<<dim3(M_ / 16), 256, 0, stream>>>(hbuf, th, w1, Tb);
    gemm_bf16<FFN_><<<dim3(M_ / 64, D_ / 128), 256, 0, stream>>>(Tb, w2b, hbuf, out);
    ln_kernel      <<<dim3(M_ / 4), 256, 0, stream>>>(out, g2, b2, out);
}